// Round 9
// baseline (68.578 us; speedup 1.0000x reference)
//
#include <hip/hip_runtime.h>

// LambdaRankLoss: B=64, N=1024, binary relevances, SIGMA=1, NDCG@10, EPS=1e-8.
// loss = (1/num_pairs) * sum_{valid b} sum_{i in rel, j in nonrel}
//            |disc_i - disc_j| / (idcg_b + eps) * softplus(s_j - s_i)
// valid b  <=>  0 < nrel_b < N ; idcg_b = sum_{p < min(nrel_b,10)} 1/log2(p+2)
//
// Round 9 = Round 8 (67.6 us) with:
//  - scores pre-scaled by log2(e) at staging; hot loop works in log2-units:
//    t = v_exp_f32(-|z'|) directly (no per-pair mul by log2e; -abs is a free
//    input modifier), log1p-poly coeffs absorb 1/ln2, final ln2 folds into
//    the per-block double scale. ~2 fewer ops of ~12 per pair.
//  - SPLIT 16 -> 8: per-CU hot work unchanged, per-CU staging cost halved
//    (2 blocks/CU instead of 4 redundantly re-partitioning the batch).
// Two kernels, plain per-block partial stores, fixed-order reductions
// everywhere -> bitwise deterministic (tripwire-safe). No memset needed.

#define NPOS   1024
#define SPLIT  8                       // slices per batch; grid = B*SPLIT
#define KTOP   10
#define EPSF   1e-8f
#define MAXSL  ((NPOS + SPLIT - 1) / SPLIT)   // 128 rel items per slice max
#define MAXB   64
#define LOG2E  1.4426950408889634f
#define LN2    0.6931471805599453

// prefix sums of 1/log2(p+2), p=0..9: idcg = IDCG_S[min(nrel,10)]
__device__ const float IDCG_S[11] = {
    0.0f, 1.0f, 1.63092975f, 2.13092975f, 2.56160631f, 2.94845912f,
    3.30466631f, 3.63799964f, 3.95346452f, 4.25449452f, 4.54355935f
};

// softplus(z)/ln2 with z' = z*log2e:  max(z',0) + log1p(exp2(-|z'|))/ln2
// cubic fit of log1p(t)/t on (0,1], coeffs pre-divided by ln2 (abs err ~3e-4*ln2)
__device__ __forceinline__ float softplus_log2(float zp) {
    const float t = __builtin_amdgcn_exp2f(-fabsf(zp));   // v_exp, -abs folded
    const float g = t * (1.442216f + t * (-0.701718f
                  + t * (0.365639f + t * (-0.106478f))));
    return fmaxf(zp, 0.0f) + g;
}

__device__ __forceinline__ float inv_log2_f(float x) {
    return __builtin_amdgcn_rcpf(__log2f(x));   // ~1e-5 rel err, fine
}

__global__ __launch_bounds__(256) void lr_pair_kernel(
    const float* __restrict__ scores,
    const int*   __restrict__ relev,
    double*      __restrict__ partials,   // one slot per block
    unsigned*    __restrict__ pairCnt)    // one slot per batch (slice 0 writes)
{
    __shared__ __align__(16) float2 nshr[NPOS];  // nonrel (score*log2e, disc)
    __shared__ float2 rshr[MAXSL];       // this slice's rel items only
    __shared__ int    cnt[16];           // rel count per 64-item chunk
    __shared__ double wsum[4];

    const int b     = blockIdx.x / SPLIT;
    const int slice = blockIdx.x % SPLIT;
    const int tid   = threadIdx.x;
    const int lane  = tid & 63;
    const int wave  = tid >> 6;

    const float* srow = scores + (size_t)b * NPOS;
    const int*   rrow = relev  + (size_t)b * NPOS;

    // ---- Phase 1: load + per-chunk ballot counts (chunk c -> wave c&3) ----
    float sv[4], dv[4]; int rposv[4]; bool rf[4];
    #pragma unroll
    for (int it = 0; it < 4; ++it) {
        const int c = it * 4 + wave, idx = c * 64 + lane;
        sv[it] = srow[idx] * LOG2E;              // pre-scale into log2-units
        dv[it] = inv_log2_f((float)idx + 2.0f);
        const bool r = rrow[idx] > 0; rf[it] = r;
        unsigned long long m = __ballot(r);
        rposv[it] = __popcll(m & ((1ull << lane) - 1ull));
        if (lane == 0) cnt[c] = __popcll(m);
    }
    __syncthreads();

    int nrel = 0;
    #pragma unroll
    for (int c = 0; c < 16; ++c) nrel += cnt[c];  // uniform LDS broadcasts
    const int nnon = NPOS - nrel;
    const int i0 = (slice * nrel) / SPLIT;
    const int i1 = ((slice + 1) * nrel) / SPLIT;
    const int ni = i1 - i0;

    // ---- Phase 2: deterministic stable scatter, incremental prefix scan ----
    {
        int rb = 0;                                   // sum cnt[0 .. c-1]
        for (int cc = 0; cc < wave; ++cc) rb += cnt[cc];
        #pragma unroll
        for (int it = 0; it < 4; ++it) {
            const int c = it * 4 + wave;
            if (rf[it]) {
                const int p = rb + rposv[it];
                if (p >= i0 && p < i1) rshr[p - i0] = make_float2(sv[it], dv[it]);
            } else {
                nshr[c * 64 - rb + (lane - rposv[it])] = make_float2(sv[it], dv[it]);
            }
            if (it < 3) rb += cnt[c] + cnt[c+1] + cnt[c+2] + cnt[c+3];
        }
    }

    const float idcg = IDCG_S[min(nrel, KTOP)];   // uniform table load
    __syncthreads();

    double block_total = 0.0;
    if (nrel > 0 && nnon > 0 && ni > 0) {        // block-uniform condition
        const float4* nshr4 = reinterpret_cast<const float4*>(nshr);
        const int nnon2 = nnon >> 1;

        // 4 independent accumulators; fixed order -> deterministic
        float acc0 = 0.f, acc1 = 0.f, acc2 = 0.f, acc3 = 0.f;
        int i = 0;
        for (; i + 4 <= ni; i += 4) {
            const float2 a0 = rshr[i], a1 = rshr[i+1], a2 = rshr[i+2], a3 = rshr[i+3];
            for (int jj = tid; jj < nnon2; jj += 256) {
                const float4 q = nshr4[jj];      // 2 items per ds_read_b128
                acc0 += fabsf(a0.y - q.y) * softplus_log2(q.x - a0.x);
                acc1 += fabsf(a1.y - q.y) * softplus_log2(q.x - a1.x);
                acc2 += fabsf(a2.y - q.y) * softplus_log2(q.x - a2.x);
                acc3 += fabsf(a3.y - q.y) * softplus_log2(q.x - a3.x);
                acc0 += fabsf(a0.y - q.w) * softplus_log2(q.z - a0.x);
                acc1 += fabsf(a1.y - q.w) * softplus_log2(q.z - a1.x);
                acc2 += fabsf(a2.y - q.w) * softplus_log2(q.z - a2.x);
                acc3 += fabsf(a3.y - q.w) * softplus_log2(q.z - a3.x);
            }
        }
        for (; i < ni; ++i) {
            const float2 a0 = rshr[i];
            for (int jj = tid; jj < nnon2; jj += 256) {
                const float4 q = nshr4[jj];
                acc0 += fabsf(a0.y - q.y) * softplus_log2(q.x - a0.x);
                acc1 += fabsf(a0.y - q.w) * softplus_log2(q.z - a0.x);
            }
        }
        if (nnon & 1) {                          // odd tail: one pair/thread
            const float2 bj = nshr[nnon - 1];
            if (tid < ni) {
                const float2 a = rshr[tid];
                acc0 += fabsf(a.y - bj.y) * softplus_log2(bj.x - a.x);
            }
        }
        float acc = (acc0 + acc1) + (acc2 + acc3);

        // fixed-order wave shuffle reduce -> cross-wave LDS in double
        #pragma unroll
        for (int off = 32; off >= 1; off >>= 1) acc += __shfl_down(acc, off);
        if (lane == 0) wsum[wave] = (double)acc;
        __syncthreads();
        if (tid == 0)
            block_total = (wsum[0] + wsum[1] + wsum[2] + wsum[3])
                        * ((double)(1.0f / (idcg + EPSF)) * LN2);
    }

    if (tid == 0) {
        partials[blockIdx.x] = block_total;      // own slot, plain store
        if (slice == 0)
            pairCnt[b] = (nrel > 0 && nnon > 0) ? (unsigned)(nrel * nnon) : 0u;
    }
}

__global__ __launch_bounds__(256) void lr_final_kernel(
    const double*   __restrict__ partials,
    const unsigned* __restrict__ pairCnt,
    float*          __restrict__ out,
    int B, int nparts)
{
    __shared__ double    dsh[4];
    __shared__ long long psh[4];

    const int tid = threadIdx.x, lane = tid & 63, wave = tid >> 6;

    // fixed-order per-thread partial sums (nparts = 512 = 2*256)
    double tot = 0.0;
    for (int k = tid; k < nparts; k += 256) tot += partials[k];
    long long pairs = (tid < B) ? (long long)pairCnt[tid] : 0;

    #pragma unroll
    for (int off = 32; off >= 1; off >>= 1) {
        tot   += __shfl_down(tot, off);
        pairs += __shfl_down(pairs, off);
    }
    if (lane == 0) { dsh[wave] = tot; psh[wave] = pairs; }
    __syncthreads();
    if (tid == 0) {
        double    tt = dsh[0] + dsh[1] + dsh[2] + dsh[3];
        long long np = psh[0] + psh[1] + psh[2] + psh[3];
        out[0] = (np > 0) ? (float)(tt / (double)np) : 0.0f;
    }
}

extern "C" void kernel_launch(void* const* d_in, const int* in_sizes, int n_in,
                              void* d_out, int out_size, void* d_ws, size_t ws_size,
                              hipStream_t stream) {
    const float* scores = (const float*)d_in[0];
    const int*   relev  = (const int*)d_in[1];
    float*       out    = (float*)d_out;
    const int    B      = in_sizes[0] / NPOS;   // 64
    const int    nparts = B * SPLIT;            // 512

    double*   partials = (double*)d_ws;                    // nparts doubles
    unsigned* pairCnt  = (unsigned*)(partials + nparts);   // B uints
    // every read slot is written by lr_pair_kernel each call: no memset

    lr_pair_kernel<<<nparts, 256, 0, stream>>>(scores, relev, partials, pairCnt);
    lr_final_kernel<<<1, 256, 0, stream>>>(partials, pairCnt, out, B, nparts);
}

// Round 10
// 66.811 us; speedup vs baseline: 1.0264x; 1.0264x over previous
//
#include <hip/hip_runtime.h>

// LambdaRankLoss: B=64, N=1024, binary relevances, SIGMA=1, NDCG@10, EPS=1e-8.
// loss = (1/num_pairs) * sum_{valid b} sum_{i in rel, j in nonrel}
//            |disc_i - disc_j| / (idcg_b + eps) * softplus(s_j - s_i)
// valid b  <=>  0 < nrel_b < N ; idcg_b = sum_{p < min(nrel_b,10)} 1/log2(p+2)
//
// Round 10 = Round 8 (67.6 us, best) + Round 9's log2-units hot loop ONLY.
// SPLIT back to 16 (R9 showed SPLIT=8 costs ~2 us of occupancy/tail balance;
// staging redundancy is NOT the dominant term — wave parallelism is).
//  - scores pre-scaled by log2(e) at staging: t = v_exp_f32(-|z'|) directly,
//    poly coeffs absorb 1/ln2, final ln2 folds into per-block double scale
//  - softplus via cubic log1p fit (no v_log per pair)
//  - float4 LDS reads (2 nonrel items per ds_read_b128)
//  - idcg from constant prefix table
// Two kernels, plain per-block partial stores, fixed-order reductions
// everywhere -> bitwise deterministic (tripwire-safe). No memset needed.

#define NPOS   1024
#define SPLIT  16                      // slices per batch; grid = B*SPLIT
#define KTOP   10
#define EPSF   1e-8f
#define MAXSL  ((NPOS + SPLIT - 1) / SPLIT)   // 64 rel items per slice max
#define MAXB   64
#define LOG2E  1.4426950408889634f
#define LN2    0.6931471805599453

// prefix sums of 1/log2(p+2), p=0..9: idcg = IDCG_S[min(nrel,10)]
__device__ const float IDCG_S[11] = {
    0.0f, 1.0f, 1.63092975f, 2.13092975f, 2.56160631f, 2.94845912f,
    3.30466631f, 3.63799964f, 3.95346452f, 4.25449452f, 4.54355935f
};

// softplus(z)/ln2 with z' = z*log2e:  max(z',0) + log1p(exp2(-|z'|))/ln2
// cubic fit of log1p(t)/t on (0,1], coeffs pre-divided by ln2 (abs err ~5e-4)
__device__ __forceinline__ float softplus_log2(float zp) {
    const float t = __builtin_amdgcn_exp2f(-fabsf(zp));   // v_exp, -abs folded
    const float g = t * (1.442216f + t * (-0.701718f
                  + t * (0.365639f + t * (-0.106478f))));
    return fmaxf(zp, 0.0f) + g;
}

__device__ __forceinline__ float inv_log2_f(float x) {
    return __builtin_amdgcn_rcpf(__log2f(x));   // ~1e-5 rel err, fine
}

__global__ __launch_bounds__(256) void lr_pair_kernel(
    const float* __restrict__ scores,
    const int*   __restrict__ relev,
    double*      __restrict__ partials,   // one slot per block
    unsigned*    __restrict__ pairCnt)    // one slot per batch (slice 0 writes)
{
    __shared__ __align__(16) float2 nshr[NPOS];  // nonrel (score*log2e, disc)
    __shared__ float2 rshr[MAXSL];       // this slice's rel items only
    __shared__ int    cnt[16];           // rel count per 64-item chunk
    __shared__ double wsum[4];

    const int b     = blockIdx.x >> 4;           // SPLIT == 16
    const int slice = blockIdx.x & (SPLIT - 1);
    const int tid   = threadIdx.x;
    const int lane  = tid & 63;
    const int wave  = tid >> 6;

    const float* srow = scores + (size_t)b * NPOS;
    const int*   rrow = relev  + (size_t)b * NPOS;

    // ---- Phase 1: load + per-chunk ballot counts (chunk c -> wave c&3) ----
    float sv[4], dv[4]; int rposv[4]; bool rf[4];
    #pragma unroll
    for (int it = 0; it < 4; ++it) {
        const int c = it * 4 + wave, idx = c * 64 + lane;
        sv[it] = srow[idx] * LOG2E;              // pre-scale into log2-units
        dv[it] = inv_log2_f((float)idx + 2.0f);
        const bool r = rrow[idx] > 0; rf[it] = r;
        unsigned long long m = __ballot(r);
        rposv[it] = __popcll(m & ((1ull << lane) - 1ull));
        if (lane == 0) cnt[c] = __popcll(m);
    }
    __syncthreads();

    int nrel = 0;
    #pragma unroll
    for (int c = 0; c < 16; ++c) nrel += cnt[c];  // uniform LDS broadcasts
    const int nnon = NPOS - nrel;
    const int i0 = (slice * nrel) / SPLIT;
    const int i1 = ((slice + 1) * nrel) / SPLIT;
    const int ni = i1 - i0;

    // ---- Phase 2: deterministic stable scatter, incremental prefix scan ----
    {
        int rb = 0;                                   // sum cnt[0 .. c-1]
        for (int cc = 0; cc < wave; ++cc) rb += cnt[cc];
        #pragma unroll
        for (int it = 0; it < 4; ++it) {
            const int c = it * 4 + wave;
            if (rf[it]) {
                const int p = rb + rposv[it];
                if (p >= i0 && p < i1) rshr[p - i0] = make_float2(sv[it], dv[it]);
            } else {
                nshr[c * 64 - rb + (lane - rposv[it])] = make_float2(sv[it], dv[it]);
            }
            if (it < 3) rb += cnt[c] + cnt[c+1] + cnt[c+2] + cnt[c+3];
        }
    }

    const float idcg = IDCG_S[min(nrel, KTOP)];   // uniform table load
    __syncthreads();

    double block_total = 0.0;
    if (nrel > 0 && nnon > 0 && ni > 0) {        // block-uniform condition
        const float4* nshr4 = reinterpret_cast<const float4*>(nshr);
        const int nnon2 = nnon >> 1;

        // 4 independent accumulators; fixed order -> deterministic
        float acc0 = 0.f, acc1 = 0.f, acc2 = 0.f, acc3 = 0.f;
        int i = 0;
        for (; i + 4 <= ni; i += 4) {
            const float2 a0 = rshr[i], a1 = rshr[i+1], a2 = rshr[i+2], a3 = rshr[i+3];
            for (int jj = tid; jj < nnon2; jj += 256) {
                const float4 q = nshr4[jj];      // 2 items per ds_read_b128
                acc0 += fabsf(a0.y - q.y) * softplus_log2(q.x - a0.x);
                acc1 += fabsf(a1.y - q.y) * softplus_log2(q.x - a1.x);
                acc2 += fabsf(a2.y - q.y) * softplus_log2(q.x - a2.x);
                acc3 += fabsf(a3.y - q.y) * softplus_log2(q.x - a3.x);
                acc0 += fabsf(a0.y - q.w) * softplus_log2(q.z - a0.x);
                acc1 += fabsf(a1.y - q.w) * softplus_log2(q.z - a1.x);
                acc2 += fabsf(a2.y - q.w) * softplus_log2(q.z - a2.x);
                acc3 += fabsf(a3.y - q.w) * softplus_log2(q.z - a3.x);
            }
        }
        for (; i < ni; ++i) {
            const float2 a0 = rshr[i];
            for (int jj = tid; jj < nnon2; jj += 256) {
                const float4 q = nshr4[jj];
                acc0 += fabsf(a0.y - q.y) * softplus_log2(q.x - a0.x);
                acc1 += fabsf(a0.y - q.w) * softplus_log2(q.z - a0.x);
            }
        }
        if (nnon & 1) {                          // odd tail: one pair/thread
            const float2 bj = nshr[nnon - 1];
            if (tid < ni) {
                const float2 a = rshr[tid];
                acc0 += fabsf(a.y - bj.y) * softplus_log2(bj.x - a.x);
            }
        }
        float acc = (acc0 + acc1) + (acc2 + acc3);

        // fixed-order wave shuffle reduce -> cross-wave LDS in double
        #pragma unroll
        for (int off = 32; off >= 1; off >>= 1) acc += __shfl_down(acc, off);
        if (lane == 0) wsum[wave] = (double)acc;
        __syncthreads();
        if (tid == 0)
            block_total = (wsum[0] + wsum[1] + wsum[2] + wsum[3])
                        * ((double)(1.0f / (idcg + EPSF)) * LN2);
    }

    if (tid == 0) {
        partials[blockIdx.x] = block_total;      // own slot, plain store
        if (slice == 0)
            pairCnt[b] = (nrel > 0 && nnon > 0) ? (unsigned)(nrel * nnon) : 0u;
    }
}

__global__ __launch_bounds__(256) void lr_final_kernel(
    const double*   __restrict__ partials,
    const unsigned* __restrict__ pairCnt,
    float*          __restrict__ out,
    int B, int nparts)
{
    __shared__ double    dsh[4];
    __shared__ long long psh[4];

    const int tid = threadIdx.x, lane = tid & 63, wave = tid >> 6;

    // fixed-order per-thread partial sums (nparts = 1024 = 4*256)
    double tot = 0.0;
    for (int k = tid; k < nparts; k += 256) tot += partials[k];
    long long pairs = (tid < B) ? (long long)pairCnt[tid] : 0;

    #pragma unroll
    for (int off = 32; off >= 1; off >>= 1) {
        tot   += __shfl_down(tot, off);
        pairs += __shfl_down(pairs, off);
    }
    if (lane == 0) { dsh[wave] = tot; psh[wave] = pairs; }
    __syncthreads();
    if (tid == 0) {
        double    tt = dsh[0] + dsh[1] + dsh[2] + dsh[3];
        long long np = psh[0] + psh[1] + psh[2] + psh[3];
        out[0] = (np > 0) ? (float)(tt / (double)np) : 0.0f;
    }
}

extern "C" void kernel_launch(void* const* d_in, const int* in_sizes, int n_in,
                              void* d_out, int out_size, void* d_ws, size_t ws_size,
                              hipStream_t stream) {
    const float* scores = (const float*)d_in[0];
    const int*   relev  = (const int*)d_in[1];
    float*       out    = (float*)d_out;
    const int    B      = in_sizes[0] / NPOS;   // 64
    const int    nparts = B * SPLIT;            // 1024

    double*   partials = (double*)d_ws;                    // nparts doubles
    unsigned* pairCnt  = (unsigned*)(partials + nparts);   // B uints
    // every read slot is written by lr_pair_kernel each call: no memset

    lr_pair_kernel<<<nparts, 256, 0, stream>>>(scores, relev, partials, pairCnt);
    lr_final_kernel<<<1, 256, 0, stream>>>(partials, pairCnt, out, B, nparts);
}